// Round 4
// baseline (158.283 us; speedup 1.0000x reference)
//
#include <hip/hip_runtime.h>
#include <hip/hip_bf16.h>

#define BB 4
#define NN 1024
#define FF 256
#define NBLK 1024
#define NTHR 256
#define PBLK 512          // packing/select group: blocks [0, 512)
#define QN   504          // pool+zero group:      blocks [512, 1016)
#define QPOOL 3584        // pool tasks owned by Q; rest done by P-help
#define SROWS 128         // select: sorted rows staged in LDS

typedef __hip_bfloat16 bf16;
typedef unsigned long long u64;
typedef unsigned int u32;
typedef unsigned short u16;
typedef unsigned char u8;

__device__ __forceinline__ bf16 f2b(float v) { return __float2bfloat16(v); }
__device__ __forceinline__ u16 f2bbits(float v) {
    bf16 h = __float2bfloat16(v);
    u16 s; __builtin_memcpy(&s, &h, 2);
    return s;
}
template <typename OT> __device__ __forceinline__ OT fromf(float v);
template <> __device__ __forceinline__ float fromf<float>(float v) { return v; }
template <> __device__ __forceinline__ bf16 fromf<bf16>(float v) { return __float2bfloat16(v); }

// Write-through stores: relaxed SYSTEM scope -> lands at the coherence point,
// never dirty in any per-XCD L2. Keeps every barrier fence-free (no wbl2/inv).
__device__ __forceinline__ void st_wt(u32* p, u32 v)   { __hip_atomic_store(p, v, __ATOMIC_RELAXED, __HIP_MEMORY_SCOPE_SYSTEM); }
__device__ __forceinline__ void st_wt(u64* p, u64 v)   { __hip_atomic_store(p, v, __ATOMIC_RELAXED, __HIP_MEMORY_SCOPE_SYSTEM); }
__device__ __forceinline__ void st_wt(int* p, int v)   { __hip_atomic_store(p, v, __ATOMIC_RELAXED, __HIP_MEMORY_SCOPE_SYSTEM); }
__device__ __forceinline__ void st_wt(float* p, float v){ __hip_atomic_store(p, v, __ATOMIC_RELAXED, __HIP_MEMORY_SCOPE_SYSTEM); }

// ---------------------------------------------------------------------------
// Fence-free tree barrier (validated round 3: relaxed agent atomics emit no
// cache-wide ops; payload ordering = write-through stores + the vmcnt(0)
// drain __syncthreads performs). reg layout, 32-int (128B) lines:
//   line 0: root | lines 1..8: flags[8] | lines 9..9+ngroups-1: group counters
// Groups of 16 blocks. Monotonic phases. Bailout -> visible failure, no hang.
// ---------------------------------------------------------------------------
__device__ __forceinline__ void tree_sync(int* reg, int idx, int ngroups, int phase) {
    __syncthreads();
    if (threadIdx.x == 0) {
        asm volatile("s_waitcnt vmcnt(0)" ::: "memory");
        int* gc = reg + 32 * (9 + (idx >> 4));
        int v = __hip_atomic_fetch_add(gc, 1, __ATOMIC_RELAXED, __HIP_MEMORY_SCOPE_AGENT);
        if (v == phase * 16 - 1) {
            int r = __hip_atomic_fetch_add(reg, 1, __ATOMIC_RELAXED, __HIP_MEMORY_SCOPE_AGENT);
            if (r == phase * ngroups - 1)
                for (int xx = 0; xx < 8; xx++)
                    __hip_atomic_store(reg + 32 * (1 + xx), phase,
                                       __ATOMIC_RELAXED, __HIP_MEMORY_SCOPE_AGENT);
        }
        int* flag = reg + 32 * (1 + (idx & 7));
        int spins = 0;
        while (__hip_atomic_load(flag, __ATOMIC_RELAXED, __HIP_MEMORY_SCOPE_AGENT) < phase) {
            if (spins < 64) __builtin_amdgcn_s_sleep(2);
            else            __builtin_amdgcn_s_sleep(16);
            if (++spins > (1 << 20)) break;
        }
        asm volatile("" ::: "memory");
    }
    __syncthreads();
}

// Deterministic ascending neighbor extraction from a 1024-bit row in LDS.
// Threads 0..15 (one per u64 word) prefix-scan popcounts, then write their
// word's set-bit indices. No atomics; FP sum order = ascending (matches ref).
__device__ __forceinline__ int build_nbr(const u64* myrow, u16* nbr, int* cntp, int t) {
    __syncthreads();                       // myrow producer -> consumers
    if (t < 16) {
        int myc = __popcll(myrow[t]);
        int ps = myc;
#pragma unroll
        for (int off = 1; off < 16; off <<= 1) {
            int v = __shfl_up(ps, off);
            if (t >= off) ps += v;
        }
        int idx = ps - myc;
        u64 m = myrow[t];
        while (m) {
            int i = __ffsll(m) - 1;
            if (idx < 192) nbr[idx] = (u16)(t * 64 + i);
            idx++;
            m &= m - 1;
        }
        if (t == 15) *cntp = ps;
    }
    __syncthreads();
    return min(*cntp, 192);
}

// Pooled x/pos for node (b,n). myrow already in LDS. 4-way unrolled
// accumulate: 4 independent loads issued per step -> latency overlap.
__device__ __forceinline__ void pool_task(int b, int n,
        const float* __restrict__ x, const float* __restrict__ pos,
        const u64* myrow, u16* nbr, int* cntp,
        float* __restrict__ xpool, float* __restrict__ pospool, int t) {
    const int c = build_nbr(myrow, nbr, cntp, t);
    const float* xr = x + (size_t)b * NN * FF;
    float acc = xr[(size_t)n * FF + t];
    int i = 0;
    for (; i + 4 <= c; i += 4) {
        float a0 = xr[(size_t)nbr[i + 0] * FF + t];
        float a1 = xr[(size_t)nbr[i + 1] * FF + t];
        float a2 = xr[(size_t)nbr[i + 2] * FF + t];
        float a3 = xr[(size_t)nbr[i + 3] * FF + t];
        acc += a0; acc += a1; acc += a2; acc += a3;
    }
    for (; i < c; i++) acc += xr[(size_t)nbr[i] * FF + t];
    st_wt(&xpool[((size_t)b * NN + n) * FF + t], acc);
    if (t < 3) {
        const size_t pb_ = (size_t)b * NN * 3;
        float pa = pos[pb_ + n * 3 + t];
        for (int j = 0; j < c; j++) pa += pos[pb_ + nbr[j] * 3 + t];
        st_wt(&pospool[((size_t)b * NN + n) * 4 + t], pa / (float)(c + 1));
    }
    __syncthreads();                       // before LDS reuse
}

// ---------------------------------------------------------------------------
// One persistent kernel. Two decoupled groups until the single global barrier:
//  P (blocks 0..511):   A pack 8 rows -> barP1 -> wait(sort) -> B 8 rows
//                       -> barP2 -> blocks 0-3 select (LDS row cache),
//                       blocks 4-511 finish pool tail from bitsA.
//  Q (blocks 512..1015): zero d_out + pool 3584 nodes from adj directly
//                        (starts at t=0, overlaps A+B+select).
//  Sort (blocks 1016..1023): rank-sort from order; done-counter handshake.
//  barG -> D: slim epilogue for k < K.
// ---------------------------------------------------------------------------
template <typename OT>
__global__ __launch_bounds__(NTHR, 4) void mega_kernel(
        const float* __restrict__ x, const float* __restrict__ adj,
        const float* __restrict__ pos, const float* __restrict__ order,
        u64* __restrict__ bitsA, u32* __restrict__ packed,
        int* __restrict__ sp2node, int* __restrict__ node2sp,
        int* __restrict__ perm, int* __restrict__ kcnt,
        float* __restrict__ xpool, float* __restrict__ pospool,
        int* __restrict__ sink, int* __restrict__ bar,
        OT* __restrict__ out, size_t out_elems)
{
    const int B = blockIdx.x, t = threadIdx.x;
    __shared__ union ShU {
        u64 keys[NN];                                   // sort: 8KB
        struct {                                        // phase B: ~6.9KB
            u64 myrow[16], incw[16], part[256];
            int s2nT[16 * 65];
            u16 nbr[192];
            int cnt;
        } pb;
        struct {                                        // pool: ~0.6KB
            u64 myrow[16];
            u16 nbr[192];
            int cnt;
        } pl;
        struct {                                        // select: ~33.8KB
            u32 stage[SROWS * 64];
            u8 selS[NN];
        } pc;
        struct {                                        // phase D: ~6.3KB
            int p[NN];
            u64 myrow[16];
            u16 sta[NN];
        } pd;
    } sh;

    int* Greg = bar;                 // global tree: 64 groups (lines 0..72)
    int* Preg = bar + 32 * 73;       // P tree: 32 groups (lines 73..113)
    int* srt  = bar + 32 * 114;      // sort-done counter

    if (B < PBLK) {
        // ---------------- P: Phase A — bit-pack 8 adj rows ----------------
        const int b = B >> 7, rbase = (B * 8) & (NN - 1);
        for (int i = 0; i < 8; i++) {
            const int r = rbase + i;
            const size_t base = (size_t)b * NN * NN + (size_t)r * NN;
            for (int q = 0; q < 4; q++) {
                int j = q * 256 + t;
                u64 bal = __ballot(adj[base + j] != 0.0f);
                if ((t & 63) == 0) st_wt(&bitsA[((size_t)b * NN + r) * 16 + (j >> 6)], bal);
            }
        }
        tree_sync(Preg, B, 32, 1);                     // all bitsA visible
        if (t == 0) {                                  // wait for sort blocks
            int spins = 0;
            while (__hip_atomic_load(srt, __ATOMIC_RELAXED, __HIP_MEMORY_SCOPE_AGENT) < 8) {
                __builtin_amdgcn_s_sleep(2);
                if (++spins > (1 << 20)) break;
            }
            asm volatile("" ::: "memory");
        }
        __syncthreads();

        // ---------------- P: Phase B — inc bits + packed rows ----------------
        for (int q = 0; q < 4; q++) {                  // s2nT once per block
            int j = q * 256 + t;
            sh.pb.s2nT[(j & 15) * 65 + (j >> 4)] = sp2node[b * NN + j];
        }
        for (int rr = 0; rr < 8; rr++) {
            const int r = rbase + rr;
            if (t < 16) sh.pb.myrow[t] = bitsA[((size_t)b * NN + r) * 16 + t];
            const int c = build_nbr(sh.pb.myrow, sh.pb.nbr, &sh.pb.cnt, t);
            {   // parallel OR of neighbor rows: t = g*16 + w
                const int w = t & 15, g = t >> 4;
                u64 v = 0;
                for (int n2 = g; n2 < c; n2 += 16)
                    v |= bitsA[((size_t)b * NN + sh.pb.nbr[n2]) * 16 + w];
                sh.pb.part[t] = v;
            }
            __syncthreads();
            if (t < 16) {
                u64 acc = sh.pb.myrow[t];
                for (int g = 0; g < 16; g++) acc |= sh.pb.part[g * 16 + t];
                sh.pb.incw[t] = acc;
            }
            __syncthreads();
            if (t < 64) {
                const int s = node2sp[b * NN + r];
                u32 e16 = 0, i16 = 0;
                for (int q = 0; q < 16; q++) {
                    int jn = sh.pb.s2nT[q * 65 + t];
                    u32 eb = (u32)((sh.pb.myrow[jn >> 6] >> (jn & 63)) & 1) | (u32)(jn == r);
                    u32 ib = (u32)((sh.pb.incw[jn >> 6] >> (jn & 63)) & 1);
                    e16 |= eb << q;
                    i16 |= ib << q;
                }
                st_wt(&packed[((size_t)b * NN + s) * 64 + t], e16 | (i16 << 16));
            }
            __syncthreads();
        }
        tree_sync(Preg, B, 32, 2);                     // all packed visible

        if (B < 4) {
            // ---------------- select, with LDS cache of first SROWS rows ----------------
            const int sb = B;
            const u32* pk = packed + (size_t)sb * NN * 64;
            u32 acc = 0;
            for (int i = t; i < NN * 16; i += NTHR) {  // warm L2 + stage low rows
                uint4 v = ((const uint4*)pk)[i];
                if ((i >> 4) < SROWS) ((uint4*)sh.pc.stage)[i] = v;
                acc ^= v.x ^ v.y ^ v.z ^ v.w;
            }
            if (acc == 0xDEADBEEFu) atomicAdd(sink, 1);
            __syncthreads();

            if (t < 64) {
                const int l = t;
                u32 avail = 0xFFFFu, front = (l == 0) ? 1u : 0u, sel = 0u;
                int cur = 0;                           // sorted pos 0 = argmin(order)
                for (int iter = 0; iter < 2 * NN + 8; ++iter) {
                    if ((cur >> 4) == l) sel |= 1u << (cur & 15);
                    u32 p;
                    if (cur < SROWS) p = sh.pc.stage[cur * 64 + l];     // ~LDS latency
                    else             p = pk[(size_t)cur * 64 + l];      // L2-warm
                    avail &= ~(p & 0xFFFFu);           // exc (incl. diag)
                    front = (front | (p >> 16)) & avail;
                    u64 fb = __ballot(front != 0u);
                    if (!fb) {                         // fused restart
                        front = avail;
                        fb = __ballot(front != 0u);
                        if (!fb) break;
                    }
                    int lf = __ffsll(fb) - 1;
                    u32 f = (u32)__builtin_amdgcn_readlane((int)front, lf);
                    cur = lf * 16 + (__ffs(f) - 1);
                }
                for (int q = 0; q < 16; q++) sh.pc.selS[l * 16 + q] = (sel >> q) & 1u;
            }
            __syncthreads();
            if (t < 64) {
                const int l = t;
                u32 nodesel = 0;
                const int* n2s = node2sp + sb * NN;
                for (int q = 0; q < 16; q++)
                    nodesel |= ((u32)sh.pc.selS[n2s[l * 16 + q]]) << q;
                int cnt_sel = __popc(nodesel);
                int ps = cnt_sel;
                for (int off = 1; off < 64; off <<= 1) {
                    int v = __shfl_up(ps, off);
                    if (l >= off) ps += v;
                }
                const int K = __shfl(ps, 63);
                int pos_ = ps - cnt_sel;
                u32 m = nodesel;
                while (m) { int i = __ffs(m) - 1; st_wt(&perm[sb * NN + pos_], l * 16 + i); pos_++; m &= m - 1; }
                int posu = K + l * 16 - (ps - cnt_sel);
                m = (~nodesel) & 0xFFFFu;
                while (m) { int i = __ffs(m) - 1; st_wt(&perm[sb * NN + posu], l * 16 + i); posu++; m &= m - 1; }
                if (l == 0) st_wt(&kcnt[sb], K);
            }
        } else {
            // ---------------- P-help: pool tail from bitsA ----------------
            for (int task = QPOOL + (B - 4); task < BB * NN; task += PBLK - 4) {
                const int tb = task & 3, n = task >> 2;
                if (t < 16) sh.pl.myrow[t] = bitsA[((size_t)tb * NN + n) * 16 + t];
                pool_task(tb, n, x, pos, sh.pl.myrow, sh.pl.nbr, &sh.pl.cnt,
                          xpool, pospool, t);
            }
        }
    } else if (B < PBLK + QN) {
        // ---------------- Q: zero d_out + pool from adj (starts at t=0) ----------------
        const int zi = B - PBLK;
        const size_t nb8 = (out_elems * sizeof(OT)) >> 3;
        u64* o8 = (u64*)out;
        for (size_t i = (size_t)zi * NTHR + t; i < nb8; i += (size_t)QN * NTHR)
            st_wt(o8 + i, (u64)0);
        for (int task = zi; task < QPOOL; task += QN) {
            const int tb = task & 3, n = task >> 2;
            const size_t abase = (size_t)tb * NN * NN + (size_t)n * NN;
            for (int q = 0; q < 4; q++) {              // scan adj row directly
                int j = q * 256 + t;
                u64 bal = __ballot(adj[abase + j] != 0.0f);
                if ((t & 63) == 0) sh.pl.myrow[j >> 6] = bal;
            }
            pool_task(tb, n, x, pos, sh.pl.myrow, sh.pl.nbr, &sh.pl.cnt,
                      xpool, pospool, t);
        }
    } else {
        // ---------------- sort blocks (1016..1023): rank sort from order ----------------
        const int b = (B - (PBLK + QN)) >> 1, half = (B - (PBLK + QN)) & 1;
        for (int i = t; i < NN; i += NTHR) {
            float v = order[(size_t)b * NN + i];
            u32 ub = __float_as_uint(v);
            u32 sk = (ub & 0x80000000u) ? ~ub : (ub | 0x80000000u);
            sh.keys[i] = ((u64)sk << 32) | (u32)i;     // strict total order
        }
        __syncthreads();
        u64 mk0 = sh.keys[half * 512 + t], mk1 = sh.keys[half * 512 + 256 + t];
        int r0 = 0, r1 = 0;
        for (int m = 0; m < NN; m++) {                 // LDS broadcast reads
            u64 v = sh.keys[m];
            r0 += (v < mk0);
            r1 += (v < mk1);
        }
        int n0 = (int)(mk0 & 0xFFFFFFFFu), n1 = (int)(mk1 & 0xFFFFFFFFu);
        st_wt(&sp2node[b * NN + r0], n0); st_wt(&node2sp[b * NN + n0], r0);
        st_wt(&sp2node[b * NN + r1], n1); st_wt(&node2sp[b * NN + n1], r1);
        __syncthreads();                               // drain all waves' stores
        if (t == 0)
            __hip_atomic_fetch_add(srt, 1, __ATOMIC_RELAXED, __HIP_MEMORY_SCOPE_AGENT);
    }

    tree_sync(Greg, B, 64, 1);                         // everything visible

    // ---------------- Phase D: slim epilogue (k < K only) ----------------
    OT* out_x = out;
    OT* out_pos = out_x + (size_t)BB * NN * FF;
    OT* out_a = out_pos + (size_t)BB * NN * 3;
    OT* out_mask = out_a + (size_t)BB * NN * NN;

    for (int task = B; task < BB * NN; task += NBLK) {
        const int b = task & 3, k = task >> 2;
        const int K = kcnt[b];
        if (k >= K) continue;                          // block-uniform
        const int r = perm[b * NN + k];
        OT* ox = out_x + ((size_t)b * NN + k) * FF;
        OT* op = out_pos + ((size_t)b * NN + k) * 3;
        OT* oa = out_a + ((size_t)b * NN + k) * NN;
        if (t == 0) out_mask[(size_t)b * NN + k] = fromf<OT>(1.0f);
        if (t < 16) sh.pd.myrow[t] = bitsA[((size_t)b * NN + r) * 16 + t];
        for (int q = 0; q < 4; q++) { int j = t + q * 256; sh.pd.p[j] = perm[b * NN + j]; }
        __syncthreads();

        // x_p / pos_p: gather pooled rows
        if constexpr (sizeof(OT) == 2) {
            if (t < 32) {
                const float* xr = xpool + ((size_t)b * NN + r) * FF + t * 8;
                union { u16 w[8]; uint4 v; } u;
#pragma unroll
                for (int i = 0; i < 8; i++) u.w[i] = f2bbits(xr[i]);
                ((uint4*)ox)[t] = u.v;
            }
        } else {
            ox[t] = (OT)xpool[((size_t)b * NN + r) * FF + t];
        }
        if (t < 3) op[t] = fromf<OT>(pospool[((size_t)b * NN + r) * 4 + t]);

        // coarse adj row: adj2[r,pj] = A[r,pj] + popc(row_r & row_pj)
        if constexpr (sizeof(OT) == 2) {
            for (int q = 0; q < 4; q++) {
                int jj = t + q * 256;
                float v = 0.0f;
                if (jj < K) {
                    const int pj = sh.pd.p[jj];
                    const u64* rj = bitsA + ((size_t)b * NN + pj) * 16;
                    int a2 = (int)((sh.pd.myrow[pj >> 6] >> (pj & 63)) & 1);
#pragma unroll
                    for (int w = 0; w < 16; w++)
                        a2 += __popcll(sh.pd.myrow[w] & rj[w]);
                    v = (float)a2;
                }
                sh.pd.sta[jj] = f2bbits(v);
            }
            __syncthreads();
            const int nu = (K + 7) >> 3;               // prefix only; tail pre-zeroed
            if (t < nu) ((uint4*)oa)[t] = ((const uint4*)sh.pd.sta)[t];
            __syncthreads();
        } else {
            for (int q = 0; q < 4; q++) {
                int jj = t + q * 256;
                if (jj < K) {
                    const int pj = sh.pd.p[jj];
                    const u64* rj = bitsA + ((size_t)b * NN + pj) * 16;
                    int a2 = (int)((sh.pd.myrow[pj >> 6] >> (pj & 63)) & 1);
#pragma unroll
                    for (int w = 0; w < 16; w++)
                        a2 += __popcll(sh.pd.myrow[w] & rj[w]);
                    oa[jj] = (float)a2;
                }
            }
            __syncthreads();
        }
    }
}

extern "C" void kernel_launch(void* const* d_in, const int* in_sizes, int n_in,
                              void* d_out, int out_size, void* d_ws, size_t ws_size,
                              hipStream_t stream) {
    const float* x     = (const float*)d_in[0];  // [B,N,F]
    const float* adj   = (const float*)d_in[1];  // [B,N,N]
    const float* pos   = (const float*)d_in[2];  // [B,N,3]
    const float* order = (const float*)d_in[3];  // [B,N]
    // d_in[4] = node_mask: all-true; ignored.

    char* ws = (char*)d_ws;
    size_t off = 0;
    u64* bitsA     = (u64*)(ws + off);  off += (size_t)BB * NN * 16 * 8;   // 512 KiB
    u32* packed    = (u32*)(ws + off);  off += (size_t)BB * NN * 64 * 4;   // 1 MiB
    int* sp2node   = (int*)(ws + off);  off += (size_t)BB * NN * 4;
    int* node2sp   = (int*)(ws + off);  off += (size_t)BB * NN * 4;
    int* perm      = (int*)(ws + off);  off += (size_t)BB * NN * 4;
    int* kcnt      = (int*)(ws + off);  off += 64;
    int* sink      = (int*)(ws + off);  off += 64;    // DCE-defeat, never read
    float* xpool   = (float*)(ws + off); off += (size_t)BB * NN * FF * 4;  // 4 MiB
    float* pospool = (float*)(ws + off); off += (size_t)BB * NN * 4 * 4;   // 64 KiB
    int* bar       = (int*)(ws + off);  off += 16384; // barrier trees + sort flag

    hipMemsetAsync(bar, 0, 16384, stream);            // ws is poisoned; needs 0

    bool outf32 = false;
    size_t osz = 0;
    if (hipMemPtrGetInfo(d_out, &osz) == hipSuccess)
        outf32 = (osz >= 4ull * (size_t)out_size);

    if (outf32)
        mega_kernel<float><<<NBLK, NTHR, 0, stream>>>(x, adj, pos, order, bitsA, packed,
            sp2node, node2sp, perm, kcnt, xpool, pospool, sink, bar,
            (float*)d_out, (size_t)out_size);
    else
        mega_kernel<bf16><<<NBLK, NTHR, 0, stream>>>(x, adj, pos, order, bitsA, packed,
            sp2node, node2sp, perm, kcnt, xpool, pospool, sink, bar,
            (bf16*)d_out, (size_t)out_size);
}